// Round 4
// baseline (357.415 us; speedup 1.0000x reference)
//
#include <hip/hip_runtime.h>
#include <stdint.h>

// Segment layout (elements in each battle row of 10451 floats):
//  player 9 @0 | status 86 @9 | pinfo 8 @95 | 13 x card(740) @103 | potions 43 @9723
//  | relics 180 @9766 | 5 x monster(101) @9946
// Output row (542 floats): player4 @0 | status16 @4 | pinfo2 @20 | cards 13*32 @22
//  | potions8 @438 | relics16 @446 | monsters 5*16 @462
//
// Strategy: no LDS, no barriers. Each wave owns 32 A-rows of one segment and
// loads MFMA fragments straight from global (dwordx4, 4B-aligned legal) in
// BK=128 chunks -> per-row 512B touches (1.125x sector overfetch vs 1.5x for
// 128B touches). W is pre-packed to bf16, zero-padded to K_pad (mult of 128),
// 16B-aligned rows, NOUT padded to 16/32 -> no k/col predication in the hot
// loop; only the allocation-end guard on A (redirect to a zero page).

typedef __attribute__((ext_vector_type(8))) short short8;
typedef __attribute__((ext_vector_type(4))) float f32x4;
typedef __attribute__((ext_vector_type(4), aligned(4))) float f32x4u; // 4B-aligned vector load

#define TOTAL_ELS (32768u * 10451u)

__device__ inline unsigned short f2bf(float f) {
  union { float f; uint32_t u; } v; v.f = f;
  uint32_t r = v.u + 0x7FFFu + ((v.u >> 16) & 1u);   // round-to-nearest-even
  return (unsigned short)(r >> 16);
}

// ---- W pre-pack: fp32 [NOUT][K] -> bf16 [NP][K_pad], zero-padded ----
// region table (element offsets in the packed buffer):
//  player  NP=16 Kp=128 @0      | status NP=16 Kp=128 @2048 | pinfo NP=16 Kp=128 @4096
//  card    NP=32 Kp=768 @6144   | potions NP=16 Kp=128 @30720
//  relics  NP=16 Kp=256 @32768  | monster NP=16 Kp=128 @36864   (total 38912 els)
__global__ __launch_bounds__(256) void pack_w(
    const float* __restrict__ Wp, const float* __restrict__ Ws,
    const float* __restrict__ Wpi, const float* __restrict__ Wc,
    const float* __restrict__ Wpo, const float* __restrict__ Wr,
    const float* __restrict__ Wm, unsigned short* __restrict__ wout)
{
  int el = blockIdx.x * 256 + threadIdx.x;
  if (el >= 38912) return;
  const float* w; int NOUT, K, Kp, woff;
  if (el < 2048)       { w = Wp;  NOUT = 4;  K = 9;   Kp = 128; woff = 0; }
  else if (el < 4096)  { w = Ws;  NOUT = 16; K = 86;  Kp = 128; woff = 2048; }
  else if (el < 6144)  { w = Wpi; NOUT = 2;  K = 8;   Kp = 128; woff = 4096; }
  else if (el < 30720) { w = Wc;  NOUT = 32; K = 740; Kp = 768; woff = 6144; }
  else if (el < 32768) { w = Wpo; NOUT = 8;  K = 43;  Kp = 128; woff = 30720; }
  else if (el < 36864) { w = Wr;  NOUT = 16; K = 180; Kp = 256; woff = 32768; }
  else                 { w = Wm;  NOUT = 16; K = 101; Kp = 128; woff = 36864; }
  int rel = el - woff;
  int col = rel / Kp;
  int k   = rel - col * Kp;
  float v = (col < NOUT && k < K) ? w[col * K + k] : 0.0f;
  wout[el] = f2bf(v);
}

__global__ __launch_bounds__(256, 3) void seg_gemm(
    const float* __restrict__ battle,
    const unsigned short* __restrict__ wpack,
    float* __restrict__ out, const float* __restrict__ zpage)
{
  const int bid = blockIdx.x;
  int bloc, nsub, K, NOUT, soff, ooff, Kp, woff;
  // cards first (longest blocks), small segments tail the grid
  if (bid < 3328)      { bloc = bid;        nsub = 13; K = 740; NOUT = 32; soff = 103;  ooff = 22;  Kp = 768; woff = 6144; }
  else if (bid < 4608) { bloc = bid - 3328; nsub = 5;  K = 101; NOUT = 16; soff = 9946; ooff = 462; Kp = 128; woff = 36864; }
  else if (bid < 4864) { bloc = bid - 4608; nsub = 1;  K = 180; NOUT = 16; soff = 9766; ooff = 446; Kp = 256; woff = 32768; }
  else if (bid < 5120) { bloc = bid - 4864; nsub = 1;  K = 86;  NOUT = 16; soff = 9;    ooff = 4;   Kp = 128; woff = 2048; }
  else if (bid < 5376) { bloc = bid - 5120; nsub = 1;  K = 43;  NOUT = 8;  soff = 9723; ooff = 438; Kp = 128; woff = 30720; }
  else if (bid < 5632) { bloc = bid - 5376; nsub = 1;  K = 9;   NOUT = 4;  soff = 0;    ooff = 0;   Kp = 128; woff = 0; }
  else                 { bloc = bid - 5632; nsub = 1;  K = 8;   NOUT = 2;  soff = 95;   ooff = 20;  Kp = 128; woff = 4096; }

  const int t    = threadIdx.x;
  const int lane = t & 63;
  const int wv   = t >> 6;          // wave id 0..3; wave owns rows [mb, mb+32)
  const int rl   = lane & 15;
  const int kg   = lane >> 4;       // k-group 0..3 (8 k's each within a 32-k step)
  const int mb   = bloc * 128 + wv * 32;

  // Global element offsets of this lane's two A-rows (one per m-frag).
  uint32_t rb[2];
  #pragma unroll
  for (int mf = 0; mf < 2; ++mf) {
    uint32_t m   = (uint32_t)(mb + mf * 16 + rl);
    uint32_t b   = m / (uint32_t)nsub;
    uint32_t sub = m - b * (uint32_t)nsub;
    rb[mf] = b * 10451u + (uint32_t)soff + sub * (uint32_t)K;
  }

  const uint32_t LIM = TOTAL_ELS - 3u;   // g valid iff g+3 < TOTAL
  const int nfc = (NOUT > 16) ? 2 : 1;
  const int nch = Kp >> 7;
  const unsigned short* wbase = wpack + woff;

  f32x4 acc[2][2] = {};

  for (int ch = 0; ch < nch; ++ch) {
    const uint32_t kb = (uint32_t)(ch * 128 + kg * 8);

    // ---- A: 16 x dwordx4 direct from HBM (512B window per row per chunk) ----
    f32x4 a[2][4][2];
    #pragma unroll
    for (int mf = 0; mf < 2; ++mf)
      #pragma unroll
      for (int s = 0; s < 4; ++s)
        #pragma unroll
        for (int j = 0; j < 2; ++j) {
          uint32_t g = rb[mf] + kb + (uint32_t)(s * 32 + j * 4);
          const float* p = (g < LIM) ? (battle + g) : zpage;
          a[mf][s][j] = *(const f32x4u*)p;
        }

    // ---- W: bf16 fragments, 16B-aligned, L1/L2-hot ----
    short8 wf[2][4];
    #pragma unroll
    for (int nf = 0; nf < 2; ++nf) {
      if (nf < nfc) {
        #pragma unroll
        for (int s = 0; s < 4; ++s) {
          const unsigned short* p = wbase + (uint32_t)((nf * 16 + rl) * Kp) + kb + (uint32_t)(s * 32);
          wf[nf][s] = *(const short8*)p;
        }
      }
    }

    // ---- convert + MFMA ----
    #pragma unroll
    for (int s = 0; s < 4; ++s) {
      #pragma unroll
      for (int mf = 0; mf < 2; ++mf) {
        f32x4 lo = a[mf][s][0], hi = a[mf][s][1];
        short8 aa;
        aa[0] = (short)f2bf(lo[0]); aa[1] = (short)f2bf(lo[1]);
        aa[2] = (short)f2bf(lo[2]); aa[3] = (short)f2bf(lo[3]);
        aa[4] = (short)f2bf(hi[0]); aa[5] = (short)f2bf(hi[1]);
        aa[6] = (short)f2bf(hi[2]); aa[7] = (short)f2bf(hi[3]);
        #pragma unroll
        for (int nf = 0; nf < 2; ++nf)
          if (nf < nfc)
            acc[mf][nf] = __builtin_amdgcn_mfma_f32_16x16x32_bf16(aa, wf[nf][s], acc[mf][nf], 0, 0, 0);
      }
    }
  }

  // ---- epilogue: C/D layout col = lane&15, row = (lane>>4)*4 + q ----
  #pragma unroll
  for (int mf = 0; mf < 2; ++mf) {
    #pragma unroll
    for (int q = 0; q < 4; ++q) {
      uint32_t m   = (uint32_t)(mb + mf * 16 + kg * 4 + q);
      uint32_t b   = m / (uint32_t)nsub;
      uint32_t sub = m - b * (uint32_t)nsub;
      uint32_t ob  = b * 542u + (uint32_t)ooff + sub * (uint32_t)NOUT;
      #pragma unroll
      for (int nf = 0; nf < 2; ++nf) {
        if (nf < nfc) {
          const int col = nf * 16 + rl;
          if (col < NOUT) out[ob + col] = acc[mf][nf][q];
        }
      }
    }
  }
}

extern "C" void kernel_launch(void* const* d_in, const int* in_sizes, int n_in,
                              void* d_out, int out_size, void* d_ws, size_t ws_size,
                              hipStream_t stream) {
  const float* battle   = (const float*)d_in[0];
  const float* Wplayer  = (const float*)d_in[1];
  const float* Wstatus  = (const float*)d_in[2];
  const float* Wpinfo   = (const float*)d_in[3];
  const float* Wcard    = (const float*)d_in[4];
  const float* Wpotions = (const float*)d_in[5];
  const float* Wrelics  = (const float*)d_in[6];
  const float* Wmonster = (const float*)d_in[7];
  float* out = (float*)d_out;

  // ws layout: [0,256) zero page | [256, 256+77824) packed bf16 W
  const float* zpage = (const float*)d_ws;
  unsigned short* wpack = (unsigned short*)((char*)d_ws + 256);

  hipMemsetAsync(d_ws, 0, 256, stream);
  hipLaunchKernelGGL(pack_w, dim3(152), dim3(256), 0, stream,
                     Wplayer, Wstatus, Wpinfo, Wcard, Wpotions, Wrelics,
                     Wmonster, wpack);
  hipLaunchKernelGGL(seg_gemm, dim3(5888), dim3(256), 0, stream,
                     battle, (const unsigned short*)wpack, out, zpage);
}

// Round 5
// 309.238 us; speedup vs baseline: 1.1558x; 1.1558x over previous
//
#include <hip/hip_runtime.h>
#include <stdint.h>

// Segment layout (elements in each battle row of 10451 floats):
//  player 9 @0 | status 86 @9 | pinfo 8 @95 | 13 x card(740) @103 | potions 43 @9723
//  | relics 180 @9766 | 5 x monster(101) @9946
// Output row (542 floats): player4 @0 | status16 @4 | pinfo2 @20 | cards 13*32 @22
//  | potions8 @438 | relics16 @446 | monsters 5*16 @462
//
// Card path (92% of bytes): block = 2 battle rows. Stage each row's card
// region as ONE contiguous span (38 x 1KB coalesced global_load_lds rounds,
// no k-windows -> no sector overfetch), then 6 K-chunks of MFMA straight from
// LDS (read-only after a single barrier). Waves: (m-span, n-half). W is
// pre-packed to a fragment-interleaved bf16 layout so each W fragment load is
// one contiguous 1KB wave-instruction. Small segments keep the R1 windowed-LDS
// path (8% of bytes).

typedef __attribute__((ext_vector_type(8))) short short8;
typedef __attribute__((ext_vector_type(4))) float f32x4;

#define TOTAL_ELS (32768u * 10451u)

__device__ inline unsigned short f2bf(float f) {
  union { float f; uint32_t u; } v; v.f = f;
  uint32_t r = v.u + 0x7FFFu + ((v.u >> 16) & 1u);   // round-to-nearest-even
  return (unsigned short)(r >> 16);
}

__device__ inline void gload_dw(const float* g, float* lds) {
  __builtin_amdgcn_global_load_lds(
      (const __attribute__((address_space(1))) void*)g,
      (__attribute__((address_space(3))) void*)lds, 4, 0, 0);
}

// Card W -> fragment-interleaved bf16: dword idx = cs*512 + wn*256 + kg*64 + rl*4 + d
// where cs = ch*4+s (0..23). Element maps to n = wn*16+rl, k = ch*128+s*32+kg*8+d*2.
// Zero-padded for k >= 740. 12288 dwords = 48 KB.
__global__ __launch_bounds__(256) void pack_w(const float* __restrict__ Wc,
                                              uint32_t* __restrict__ wout) {
  int el = blockIdx.x * 256 + threadIdx.x;
  if (el >= 12288) return;
  int d  = el & 3;
  int rl = (el >> 2) & 15;
  int kg = (el >> 6) & 3;
  int wn = (el >> 8) & 1;
  int cs = el >> 9;
  int s  = cs & 3, ch = cs >> 2;
  int n  = wn * 16 + rl;
  int k  = ch * 128 + s * 32 + kg * 8 + d * 2;
  float v0 = (k     < 740) ? Wc[n * 740 + k]     : 0.0f;
  float v1 = (k + 1 < 740) ? Wc[n * 740 + k + 1] : 0.0f;
  wout[el] = (uint32_t)f2bf(v0) | ((uint32_t)f2bf(v1) << 16);
}

__global__ __launch_bounds__(256, 2) void seg_gemm(
    const float* __restrict__ battle,
    const float* __restrict__ Wplayer, const float* __restrict__ Wstatus,
    const float* __restrict__ Wpinfo,  const float* __restrict__ Wpotions,
    const float* __restrict__ Wrelics, const float* __restrict__ Wmonster,
    const uint32_t* __restrict__ wpack2,
    float* __restrict__ out, const float* __restrict__ zpage)
{
  __shared__ float shm[19456];   // 77824 B. card: [2][9728]; small: a[4096] + w[1024]
  const int bid = blockIdx.x;
  const int t    = threadIdx.x;
  const int lane = t & 63;
  const int wv   = t >> 6;
  const int rl   = lane & 15;
  const int kg   = lane >> 4;

  if (bid < 16384) {
    // ======================= card path =======================
    const uint32_t g0 = (uint32_t)(bid * 2) * 10451u + 103u;
    const uint32_t g1 = g0 + 10451u;
    #pragma unroll
    for (int r = 0; r < 38; ++r)
      gload_dw(battle + g0 + (uint32_t)(r * 256 + t), &shm[r * 256 + t]);
    #pragma unroll
    for (int r = 0; r < 38; ++r)
      gload_dw(battle + g1 + (uint32_t)(r * 256 + t), &shm[9728 + r * 256 + t]);
    __syncthreads();   // compiler drains vmcnt(0); LDS read-only afterwards

    const int wm = wv >> 1;           // which battle row (span)
    const int wn = wv & 1;            // which n-half of the 32 outputs
    const float* aspan = &shm[wm * 9728];
    const uint32_t abase = (rl < 13) ? (uint32_t)(rl * 740) : 0u;  // dead rows -> word 0

    f32x4 acc = {0.f, 0.f, 0.f, 0.f};
    for (int ch = 0; ch < 6; ++ch) {
      #pragma unroll
      for (int s = 0; s < 4; ++s) {
        const float* ap = aspan + abase + (uint32_t)(ch * 128 + s * 32 + kg * 8);
        f32x4 lo = *(const f32x4*)ap;
        f32x4 hi = *(const f32x4*)(ap + 4);
        short8 aa;
        aa[0] = (short)f2bf(lo[0]); aa[1] = (short)f2bf(lo[1]);
        aa[2] = (short)f2bf(lo[2]); aa[3] = (short)f2bf(lo[3]);
        aa[4] = (short)f2bf(hi[0]); aa[5] = (short)f2bf(hi[1]);
        aa[6] = (short)f2bf(hi[2]); aa[7] = (short)f2bf(hi[3]);
        const int cs = ch * 4 + s;
        short8 wf = *(const short8*)(wpack2 + (uint32_t)(cs * 512 + wn * 256 + kg * 64 + rl * 4));
        acc = __builtin_amdgcn_mfma_f32_16x16x32_bf16(aa, wf, acc, 0, 0, 0);
      }
    }

    // C/D: col = lane&15 = rl (n), row = kg*4+q (sub). Rows 13..15 discarded.
    const uint32_t b = (uint32_t)(bid * 2 + wm);
    #pragma unroll
    for (int q = 0; q < 4; ++q) {
      const int sub = kg * 4 + q;
      if (sub < 13)
        out[b * 542u + 22u + (uint32_t)(sub * 32 + wn * 16 + rl)] = acc[q];
    }
    return;
  }

  // ======================= small-segment path (R1 structure) =======================
  const int sb = bid - 16384;
  int bloc, nsub, K, NOUT, soff, ooff;
  const float* wp;
  if (sb < 1280)      { bloc = sb;        nsub = 5; K = 101; NOUT = 16; soff = 9946; ooff = 462; wp = Wmonster; }
  else if (sb < 1536) { bloc = sb - 1280; nsub = 1; K = 180; NOUT = 16; soff = 9766; ooff = 446; wp = Wrelics; }
  else if (sb < 1792) { bloc = sb - 1536; nsub = 1; K = 86;  NOUT = 16; soff = 9;    ooff = 4;   wp = Wstatus; }
  else if (sb < 2048) { bloc = sb - 1792; nsub = 1; K = 43;  NOUT = 8;  soff = 9723; ooff = 438; wp = Wpotions; }
  else if (sb < 2304) { bloc = sb - 2048; nsub = 1; K = 9;   NOUT = 4;  soff = 0;    ooff = 0;   wp = Wplayer; }
  else                { bloc = sb - 2304; nsub = 1; K = 8;   NOUT = 2;  soff = 95;   ooff = 20;  wp = Wpinfo; }

  float* lds_a = shm;            // [128][32] fp32, 16B-granule XOR-swizzled
  float* lds_w = shm + 4096;     // [32][32]

  const int mb = bloc * 128;
  const int r0 = t >> 5;

  uint32_t rb[16];
  #pragma unroll
  for (int i = 0; i < 16; ++i) {
    uint32_t m   = (uint32_t)(mb + r0 + 8 * i);
    uint32_t b   = m / (uint32_t)nsub;
    uint32_t sub = m - b * (uint32_t)nsub;
    rb[i] = b * 10451u + (uint32_t)soff + sub * (uint32_t)K;
  }

  const int klin = t & 31;
  const int lk   = (((klin >> 2) ^ r0) << 2) | (klin & 3);

  f32x4 acc[2] = {};
  const int nch = (K + 31) >> 5;

  for (int ch = 0; ch < nch; ++ch) {
    const int kk = (ch << 5) + lk;
    #pragma unroll
    for (int i = 0; i < 16; ++i) {
      const float* sp = (kk < K) ? (battle + rb[i] + kk) : zpage;
      gload_dw(sp, &lds_a[i * 256 + t]);
    }
    #pragma unroll
    for (int i = 0; i < 4; ++i) {
      const int col = r0 + 8 * i;
      const float* sp = (col < NOUT && kk < K) ? (wp + col * K + kk) : zpage;
      gload_dw(sp, &lds_w[i * 256 + t]);
    }
    __syncthreads();

    short8 af[2], bfr;
    #pragma unroll
    for (int mf = 0; mf < 2; ++mf) {
      const int r  = wv * 32 + mf * 16 + rl;
      const int g0i = (2 * kg) ^ (r & 7);
      const int g1i = (2 * kg + 1) ^ (r & 7);
      f32x4 lo = *(const f32x4*)&lds_a[r * 32 + g0i * 4];
      f32x4 hi = *(const f32x4*)&lds_a[r * 32 + g1i * 4];
      af[mf][0] = (short)f2bf(lo[0]); af[mf][1] = (short)f2bf(lo[1]);
      af[mf][2] = (short)f2bf(lo[2]); af[mf][3] = (short)f2bf(lo[3]);
      af[mf][4] = (short)f2bf(hi[0]); af[mf][5] = (short)f2bf(hi[1]);
      af[mf][6] = (short)f2bf(hi[2]); af[mf][7] = (short)f2bf(hi[3]);
    }
    {
      const int c   = rl;            // NOUT <= 16 for all small segments
      const int g0i = (2 * kg) ^ (c & 7);
      const int g1i = (2 * kg + 1) ^ (c & 7);
      f32x4 lo = *(const f32x4*)&lds_w[c * 32 + g0i * 4];
      f32x4 hi = *(const f32x4*)&lds_w[c * 32 + g1i * 4];
      bfr[0] = (short)f2bf(lo[0]); bfr[1] = (short)f2bf(lo[1]);
      bfr[2] = (short)f2bf(lo[2]); bfr[3] = (short)f2bf(lo[3]);
      bfr[4] = (short)f2bf(hi[0]); bfr[5] = (short)f2bf(hi[1]);
      bfr[6] = (short)f2bf(hi[2]); bfr[7] = (short)f2bf(hi[3]);
    }
    #pragma unroll
    for (int mf = 0; mf < 2; ++mf)
      acc[mf] = __builtin_amdgcn_mfma_f32_16x16x32_bf16(af[mf], bfr, acc[mf], 0, 0, 0);

    __syncthreads();
  }

  #pragma unroll
  for (int mf = 0; mf < 2; ++mf) {
    #pragma unroll
    for (int q = 0; q < 4; ++q) {
      uint32_t m   = (uint32_t)(mb + wv * 32 + mf * 16 + kg * 4 + q);
      uint32_t b   = m / (uint32_t)nsub;
      uint32_t sub = m - b * (uint32_t)nsub;
      uint32_t ob  = b * 542u + (uint32_t)ooff + sub * (uint32_t)NOUT;
      const int col = rl;
      if (col < NOUT) out[ob + col] = acc[mf][q];
    }
  }
}

extern "C" void kernel_launch(void* const* d_in, const int* in_sizes, int n_in,
                              void* d_out, int out_size, void* d_ws, size_t ws_size,
                              hipStream_t stream) {
  const float* battle   = (const float*)d_in[0];
  const float* Wplayer  = (const float*)d_in[1];
  const float* Wstatus  = (const float*)d_in[2];
  const float* Wpinfo   = (const float*)d_in[3];
  const float* Wcard    = (const float*)d_in[4];
  const float* Wpotions = (const float*)d_in[5];
  const float* Wrelics  = (const float*)d_in[6];
  const float* Wmonster = (const float*)d_in[7];
  float* out = (float*)d_out;

  // ws layout: [0,256) zero page | [256, 256+49152) frag-interleaved card W
  const float* zpage = (const float*)d_ws;
  uint32_t* wpack2 = (uint32_t*)((char*)d_ws + 256);

  hipMemsetAsync(d_ws, 0, 256, stream);
  hipLaunchKernelGGL(pack_w, dim3(48), dim3(256), 0, stream, Wcard, wpack2);
  hipLaunchKernelGGL(seg_gemm, dim3(18944), dim3(256), 0, stream,
                     battle, Wplayer, Wstatus, Wpinfo, Wpotions, Wrelics,
                     Wmonster, (const uint32_t*)wpack2, out, zpage);
}